// Round 5
// baseline (181.058 us; speedup 1.0000x reference)
//
#include <hip/hip_runtime.h>

// TT-linear v6 (bisect 2/2): v5 (hardware-PASSED, 85us) + double-buffered
// single-barrier pipeline. NO sT2 swizzle (the other suspect from v3/v4).
// Addressing is byte-identical to v5; only buffering + schedule changed.
//   G1: T1[(n1,r1),(m2,v)] = C0^T @ X-slab   (A=C0^T regs, B=xpk; K=16 pad 32)
//   G2: T2[(n2,r2),n1]/v   = C1^T @ T1       (A=C1^T regs, B=T1 LDS b128, K=128)
//   G3: Y[n3,(n1,n2)]     += C2^T @ T2       (A=C2^T regs, B=T2 LDS b128, K=32/slab)
// Phase (tok,s), ONE barrier each: G3(slab s-1 from sT2[pb^1]) | G2(slab s:
// sT1[pb]->sT2[pb]) | G1(slab s+1 -> sT1[pb^1]),  pb = s&1.
// Hazards: every RAW/WAR pair on sT1/sT2 is exactly one barrier apart; within
// a phase all concurrent accesses touch disjoint buffers.
// T1 [v][m2][n1][r1]: elem = v*S3 + m2*S2 + n1*8 + r1  (S2=136, S3=2208)
// T2 [n2][n1][v][r2]: elem = n2*R2 + n1*R1 + v*8 + r2  (R1=40,  R2=672)

typedef __attribute__((ext_vector_type(8))) short bf16x8;
typedef __attribute__((ext_vector_type(4))) float f32x4;

__device__ __forceinline__ unsigned short f2bf(float f) {
    unsigned u = __builtin_bit_cast(unsigned, f);
    u += 0x7FFFu + ((u >> 16) & 1u);   // RNE
    return (unsigned short)(u >> 16);
}

__device__ __forceinline__ unsigned f2bf_pk(float lo, float hi) {
#if __has_builtin(__builtin_amdgcn_cvt_pk_bf16_f32)
    typedef __attribute__((ext_vector_type(2))) __bf16 bf2;
    bf2 r = __builtin_amdgcn_cvt_pk_bf16_f32(lo, hi);
    return __builtin_bit_cast(unsigned, r);
#else
    return (unsigned)f2bf(lo) | ((unsigned)f2bf(hi) << 16);
#endif
}

union BF8 { bf16x8 v; unsigned short s[8]; unsigned u[4]; };
union U2  { uint2 d; unsigned u[2]; };

#define S2 136    // T1 m2-stride (elems)
#define S3 2208   // T1 v-stride  (= 16*S2 + 32 pad)
#define R1 40     // T2 n1-stride
#define R2 672    // T2 n2-stride (= 16*R1 + 32 pad)

#define MFMA32 __builtin_amdgcn_mfma_f32_16x16x32_bf16

__global__ __launch_bounds__(512, 4) void tt_mfma3_v6(
    const float* __restrict__ x, const float* __restrict__ c0,
    const float* __restrict__ c1, const float* __restrict__ c2,
    const float* __restrict__ bias, float* __restrict__ out)
{
    __shared__ __align__(16) unsigned short sT1[2][4 * S3];     // 2 x 17664 B
    __shared__ __align__(16) unsigned short sT2[2][16 * R2];    // 2 x 21504 B

    const int tid  = threadIdx.x;
    const int w    = tid >> 6;
    const int lane = tid & 63;
    const int q    = lane >> 4;
    const int c    = lane & 15;
    const int qh   = q >> 1, ql = q & 1;

    const int ct1  = w & 3;      // G1: col-tile (m2-group of 4)
    const int rtg1 = w >> 2;     // G1: row-tile group (4 tiles)
    const int rp2  = w & 3;      // G2: rt2-pair
    const int vp2  = w >> 2;     // G2: v-pair
    // G3: n2 = w*2 + t

    // ---- loop-invariant LDS element offsets (v5 verbatim, per-buffer) ----
    const int w1off = (c >> 2) * S3 + (ct1 * 4 + (c & 3)) * S2 + (rtg1 * 8 + qh) * 8 + 4 * ql;
    const int r2off = (vp2 * 2) * S3 + q * S2 + c * 8;
    const int w2off = (rp2 * 4 + qh) * R2 + c * R1 + vp2 * 16 + 4 * ql;
    const int r3off = (w * 2) * R2 + c * R1 + q * 8;
    const int xcol  = ct1 * 64 + (c & 3) * 16 + (c >> 2) * 4;   // m2*16 + v*4

    const f32x4 zero = {0.f, 0.f, 0.f, 0.f};

    // ---- x as packed-bf16 register file: xpk[s] = G1 B-fragment, slab s ----
    BF8 xpk[4];
    #pragma unroll
    for (int s = 0; s < 4; ++s)
        xpk[s].u[0] = xpk[s].u[1] = xpk[s].u[2] = xpk[s].u[3] = 0;

    auto issue_x = [&](int tb) {
        if (q < 2) {
            const float* xb = x + (size_t)(blockIdx.x * 8 + tb) * 4096;
            f32x4 t[8];
            #pragma unroll
            for (int j = 0; j < 8; ++j)
                t[j] = *(const f32x4*)&xb[(q * 8 + j) * 256 + xcol];
            #pragma unroll
            for (int s = 0; s < 4; ++s) {
                #pragma unroll
                for (int u = 0; u < 4; ++u)
                    xpk[s].u[u] = f2bf_pk(t[2 * u][s], t[2 * u + 1][s]);
            }
        }
    };

    issue_x(0);   // latency hidden under the fragment prologue

    // ---- fragment prologue (once per WG, serves 8 tokens) ----
    BF8 a0[4];                    // G1 A (C0^T), K=16 zero-padded: q>=2 rows zero
    #pragma unroll
    for (int i = 0; i < 4; ++i) {
        if (q < 2) {
            const int n1 = (rtg1 * 4 + i) * 2 + (c >> 3), r1 = c & 7;
            const float* p = &c0[(q * 8) * 128 + n1 * 8 + r1];
            #pragma unroll
            for (int u = 0; u < 4; ++u)
                a0[i].u[u] = f2bf_pk(p[(2 * u) * 128], p[(2 * u + 1) * 128]);
        } else {
            a0[i].u[0] = a0[i].u[1] = a0[i].u[2] = a0[i].u[3] = 0;
        }
    }
    BF8 aF[2][4];                 // G2 A (C1^T): k = k4*32+q*8+jj -> (m2,r1)
    #pragma unroll
    for (int i = 0; i < 2; ++i) {
        const int n2 = (rp2 * 2 + i) * 2 + (c >> 3), r2 = c & 7;
        #pragma unroll
        for (int k4 = 0; k4 < 4; ++k4) {
            const float* p = &c1[(k4 * 4 + q) * 128 + n2 * 8 + r2];
            #pragma unroll
            for (int u = 0; u < 4; ++u)
                aF[i][k4].u[u] = f2bf_pk(p[(2 * u) * 2048], p[(2 * u + 1) * 2048]);
        }
    }
    BF8 a2[4];                    // G3 A (C2^T) per slab: k = q*8+j -> (v=q, r2=j)
    #pragma unroll                //   m3 = v*4 + s  (matches xpk's m3 = (c>>2)*4+s)
    for (int s = 0; s < 4; ++s) {
        const float* p = &c2[(q * 4 + s) * 16 + c];
        #pragma unroll
        for (int u = 0; u < 4; ++u)
            a2[s].u[u] = f2bf_pk(p[(2 * u) * 256], p[(2 * u + 1) * 256]);
    }

    f32x4 acc3[2] = {zero, zero};

    // ---- stage bodies (v5 addressing; buf selects the double-buffer) ----
    auto G1 = [&](int buf, int s2) {
        #pragma unroll
        for (int i = 0; i < 4; ++i) {
            f32x4 d = MFMA32(a0[i].v, xpk[s2].v, zero, 0, 0, 0);
            U2 t; t.u[0] = f2bf_pk(d[0], d[1]); t.u[1] = f2bf_pk(d[2], d[3]);
            *(uint2*)&sT1[buf][w1off + i * 16] = t.d;   // ds_write_b64
        }
    };

    auto G2 = [&](int buf) {
        f32x4 acc2[2][2] = {{zero, zero}, {zero, zero}};
        __builtin_amdgcn_s_setprio(1);
        #pragma unroll
        for (int k4 = 0; k4 < 4; ++k4) {
            bf16x8 b0 = *(const bf16x8*)&sT1[buf][r2off + k4 * 544];
            bf16x8 b1 = *(const bf16x8*)&sT1[buf][r2off + S3 + k4 * 544];
            #pragma unroll
            for (int i = 0; i < 2; ++i) {
                acc2[i][0] = MFMA32(aF[i][k4].v, b0, acc2[i][0], 0, 0, 0);
                acc2[i][1] = MFMA32(aF[i][k4].v, b1, acc2[i][1], 0, 0, 0);
            }
        }
        __builtin_amdgcn_s_setprio(0);
        #pragma unroll
        for (int i = 0; i < 2; ++i) {
            #pragma unroll
            for (int j = 0; j < 2; ++j) {
                U2 t;
                t.u[0] = f2bf_pk(acc2[i][j][0], acc2[i][j][1]);
                t.u[1] = f2bf_pk(acc2[i][j][2], acc2[i][j][3]);
                *(uint2*)&sT2[buf][w2off + i * 1344 + j * 8] = t.d;   // ds_write_b64
            }
        }
    };

    auto G3 = [&](int buf, int sp) {
        bf16x8 b0 = *(const bf16x8*)&sT2[buf][r3off];
        bf16x8 b1 = *(const bf16x8*)&sT2[buf][r3off + R2];
        acc3[0] = MFMA32(a2[sp].v, b0, acc3[0], 0, 0, 0);
        acc3[1] = MFMA32(a2[sp].v, b1, acc3[1], 0, 0, 0);
    };

    auto epilogue = [&](int tb) {
        float* outb = out + (size_t)(blockIdx.x * 8 + tb) * 4096;
        #pragma unroll
        for (int t = 0; t < 2; ++t) {
            const int idx = c * 256 + (w * 2 + t) * 16 + 4 * q;
            f32x4 bv = *(const f32x4*)&bias[idx];
            f32x4 o = acc3[t] + bv;
            *(f32x4*)&outb[idx] = o;   // global_store_dwordx4
        }
    };

    // ---- pipelined main loop: phase (tok,s) = {G3(s-1) | G2(s) | G1(s+1)} ----
    G1(0, 0);
    __syncthreads();

    for (int tok = 0; tok < 8; ++tok) {
        #pragma unroll
        for (int s = 0; s < 4; ++s) {
            const int pb = s & 1;
            // G3 of previous slab (reads sT2[pb^1], written last phase)
            if (s == 0) {
                if (tok > 0) {
                    G3(1, 3);
                    epilogue(tok - 1);
                    acc3[0] = zero; acc3[1] = zero;
                }
            } else {
                G3(pb ^ 1, s - 1);
            }
            // prefetch + pack next token's x (consumed by this phase's G1)
            if (s == 3 && tok < 7) issue_x(tok + 1);
            // G2 of current slab (reads sT1[pb], writes sT2[pb])
            G2(pb);
            // G1 of next slab (writes sT1[pb^1])
            if (s < 3)           G1(pb ^ 1, s + 1);
            else if (tok < 7)    G1(pb ^ 1, 0);
            __syncthreads();
        }
    }
    // drain: last slab's G3 + epilogue for token 7
    G3(1, 3);
    epilogue(7);
}

extern "C" void kernel_launch(void* const* d_in, const int* in_sizes, int n_in,
                              void* d_out, int out_size, void* d_ws, size_t ws_size,
                              hipStream_t stream) {
    const float* x    = (const float*)d_in[0];
    const float* c0   = (const float*)d_in[1];  // (1,16,16,8)
    const float* c1   = (const float*)d_in[2];  // (8,16,16,8)
    const float* c2   = (const float*)d_in[3];  // (8,16,16,1)
    const float* bias = (const float*)d_in[4];  // (4096,)
    float* out = (float*)d_out;

    tt_mfma3_v6<<<512, 512, 0, stream>>>(x, c0, c1, c2, bias, out);
}